// Round 1
// baseline (335.184 us; speedup 1.0000x reference)
//
#include <hip/hip_runtime.h>

// Problem constants (from reference)
#define BATCH 32
#define NB    64
#define CH    8
#define CORE  32
#define RES   64
#define POS   16                          // (RES-CORE)/2
#define DIM   (CORE*CORE*CORE*CH)         // 262144
#define OUT_PER_B (CH*RES*RES*RES)        // 2097152

#define DPT   2                                       // d's per core thread
#define CORE_BLOCKS (DIM/(256*DPT))                   // 512

// Zero part: each thread writes F4PT float4s (128 B) -> 8x fewer workgroups
// than the previous 1-float4-per-thread version (was WG-dispatch-rate bound).
#define F4PT  8
#define TOTAL_F4 (BATCH*OUT_PER_B/4)                  // 16777216
#define ZERO_BLOCKS (TOTAL_F4/(256*F4PT))             // 8192

// Fused kernel:
//  blocks [0, CORE_BLOCKS): compute core GEMM (st staged in LDS), write placed
//  blocks [CORE_BLOCKS, ...): write float4 zeros to periphery (exact partition)
__global__ __launch_bounds__(256) void core_part_kernel(
        const float* __restrict__ U,
        const float* __restrict__ mu,
        const float* __restrict__ z,
        const float* __restrict__ L,
        float* __restrict__ out) {
    const int bid = blockIdx.x;
    if (bid < CORE_BLOCKS) {
        // ---- stage st[k*32+b] = z[b,k]*L[k] into LDS (8 KB)
        __shared__ float st[NB * BATCH];
        const int tid = threadIdx.x;
#pragma unroll
        for (int r = 0; r < 8; ++r) {
            const int idx = r * 256 + tid;   // idx = k*32 + b
            const int k = idx >> 5;
            const int b = idx & 31;
            st[idx] = z[b * NB + k] * L[k];
        }
        __syncthreads();

        // ---- core GEMM: out[b, place(d)] = sum_k st[k][b] * U[k][d] + mu[d]
        const int d0 = (bid * 256 + tid) * DPT;   // two consecutive d's
        float acc0[BATCH], acc1[BATCH];
#pragma unroll
        for (int b = 0; b < BATCH; ++b) { acc0[b] = 0.f; acc1[b] = 0.f; }

#pragma unroll 2
        for (int k = 0; k < NB; ++k) {
            const float2 u = *(const float2*)&U[(size_t)k * DIM + d0]; // coalesced
#pragma unroll
            for (int q = 0; q < 8; ++q) {
                // wave-uniform LDS address -> broadcast, conflict-free
                const float4 s = *(const float4*)&st[k * BATCH + q * 4];
                acc0[q*4+0] += s.x * u.x;  acc1[q*4+0] += s.x * u.y;
                acc0[q*4+1] += s.y * u.x;  acc1[q*4+1] += s.y * u.y;
                acc0[q*4+2] += s.z * u.x;  acc1[q*4+2] += s.z * u.y;
                acc0[q*4+3] += s.w * u.x;  acc1[q*4+3] += s.w * u.y;
            }
        }

        const float2 m = *(const float2*)&mu[d0];
        // d0 -> (c, i, j, kk) in 8x32x32x32 ; d0 even so d0,d0+1 share a row
        const int c  = d0 >> 15;
        const int i  = (d0 >> 10) & 31;
        const int j  = (d0 >> 5) & 31;
        const int kk = d0 & 31;
        const size_t o = (size_t)c * (RES * RES * RES)
                       + (size_t)(i + POS) * (RES * RES)
                       + (size_t)(j + POS) * RES
                       + (size_t)(kk + POS);
#pragma unroll
        for (int b = 0; b < BATCH; ++b) {
            float2 v = make_float2(acc0[b] + m.x, acc1[b] + m.y);
            *(float2*)&out[(size_t)b * OUT_PER_B + o] = v;   // 8B-aligned
        }
    } else {
        // ---- periphery zeroing, F4PT float4s per thread at 256-thread stride
        // (coalesced 1 KB per store instr per wave); skip float4 groups fully
        // inside the core (exact partition: kk in [16,48) == groups [4,12)).
        const size_t base = (size_t)(bid - CORE_BLOCKS) * (256 * F4PT)
                          + threadIdx.x;
        float4* o4 = (float4*)out;
        const int g = (int)(base & 15);            // k-group: invariant over s
        const bool gc = (g >= 4) & (g < 12);
        const float4 zz = make_float4(0.f, 0.f, 0.f, 0.f);
#pragma unroll
        for (int s = 0; s < F4PT; ++s) {
            const size_t p = base + (size_t)s * 256;
            const int rem = (int)(p & 65535);      // within one (b,c) 64^3/4 chunk
            const int i = rem >> 10;
            const int j = (rem >> 4) & 63;
            const bool in_core = gc & (i >= POS) & (i < POS + CORE) &
                                      (j >= POS) & (j < POS + CORE);
            if (!in_core) o4[p] = zz;
        }
    }
}

extern "C" void kernel_launch(void* const* d_in, const int* in_sizes, int n_in,
                              void* d_out, int out_size, void* d_ws, size_t ws_size,
                              hipStream_t stream) {
    const float* z  = (const float*)d_in[0];   // (32, 64)
    const float* U  = (const float*)d_in[1];   // (64, 262144)
    const float* L  = (const float*)d_in[2];   // (64,)
    const float* mu = (const float*)d_in[3];   // (262144,)
    float* out = (float*)d_out;                // (32, 8, 64, 64, 64)

    core_part_kernel<<<CORE_BLOCKS + ZERO_BLOCKS, 256, 0, stream>>>(U, mu, z, L, out);
}

// Round 3
// 333.715 us; speedup vs baseline: 1.0044x; 1.0044x over previous
//
#include <hip/hip_runtime.h>

// Problem constants (from reference)
#define BATCH 32
#define NB    64
#define CH    8
#define CORE  32
#define RES   64
#define POS   16                          // (RES-CORE)/2
#define DIM   (CORE*CORE*CORE*CH)         // 262144
#define OUT_PER_B (CH*RES*RES*RES)        // 2097152

#define DPT   2                                       // d's per core thread
#define CORE_BLOCKS (DIM/(256*DPT))                   // 512
#define UNR   8                                       // U-load prefetch depth

// Zero part: each thread writes F4PT float4s (128 B).
#define F4PT  8
#define TOTAL_F4 (BATCH*OUT_PER_B/4)                  // 16777216
#define ZERO_BLOCKS (TOTAL_F4/(256*F4PT))             // 8192

// native vector type for __builtin_nontemporal_store (HIP float4 is a class)
typedef float vfloat4 __attribute__((ext_vector_type(4)));

// Fused kernel:
//  blocks [0, CORE_BLOCKS): compute core GEMM (st staged in LDS), write placed
//  blocks [CORE_BLOCKS, ...): write float4 zeros to periphery (exact partition)
__global__ __launch_bounds__(256) void core_part_kernel(
        const float* __restrict__ U,
        const float* __restrict__ mu,
        const float* __restrict__ z,
        const float* __restrict__ L,
        float* __restrict__ out) {
    const int bid = blockIdx.x;
    if (bid < CORE_BLOCKS) {
        // ---- stage st[k*32+b] = z[b,k]*L[k] into LDS (8 KB)
        __shared__ float st[NB * BATCH];
        const int tid = threadIdx.x;
#pragma unroll
        for (int r = 0; r < 8; ++r) {
            const int idx = r * 256 + tid;   // idx = k*32 + b
            const int k = idx >> 5;
            const int b = idx & 31;
            st[idx] = z[b * NB + k] * L[k];
        }
        __syncthreads();

        // ---- core GEMM: out[b, place(d)] = sum_k st[k][b] * U[k][d] + mu[d]
        // Explicit 8-deep register prefetch of U rows: guarantees 8 global
        // loads in flight per wave while FMAs run (U is 64 MB streamed once,
        // ~900 cyc HBM latency; unroll-2 left the loop latency-bound).
        const int d0 = (bid * 256 + tid) * DPT;   // two consecutive d's
        const float* Up = &U[d0];

        float2 uf[UNR];
#pragma unroll
        for (int p = 0; p < UNR; ++p)
            uf[p] = *(const float2*)&Up[(size_t)p * DIM];

        float acc0[BATCH], acc1[BATCH];
#pragma unroll
        for (int b = 0; b < BATCH; ++b) { acc0[b] = 0.f; acc1[b] = 0.f; }

        for (int kb = 0; kb < NB; kb += UNR) {
            float2 un[UNR];
            const bool last = (kb + UNR >= NB);
            if (!last) {
#pragma unroll
                for (int p = 0; p < UNR; ++p)
                    un[p] = *(const float2*)&Up[(size_t)(kb + UNR + p) * DIM];
            }
#pragma unroll
            for (int p = 0; p < UNR; ++p) {
                const int k = kb + p;
                const float2 u = uf[p];
#pragma unroll
                for (int q = 0; q < 8; ++q) {
                    // wave-uniform LDS address -> broadcast, conflict-free
                    const float4 s = *(const float4*)&st[k * BATCH + q * 4];
                    acc0[q*4+0] += s.x * u.x;  acc1[q*4+0] += s.x * u.y;
                    acc0[q*4+1] += s.y * u.x;  acc1[q*4+1] += s.y * u.y;
                    acc0[q*4+2] += s.z * u.x;  acc1[q*4+2] += s.z * u.y;
                    acc0[q*4+3] += s.w * u.x;  acc1[q*4+3] += s.w * u.y;
                }
            }
            if (!last) {
#pragma unroll
                for (int p = 0; p < UNR; ++p) uf[p] = un[p];  // reg rename
            }
        }

        const float2 m = *(const float2*)&mu[d0];
        // d0 -> (c, i, j, kk) in 8x32x32x32 ; d0 even so d0,d0+1 share a row
        const int c  = d0 >> 15;
        const int i  = (d0 >> 10) & 31;
        const int j  = (d0 >> 5) & 31;
        const int kk = d0 & 31;
        const size_t o = (size_t)c * (RES * RES * RES)
                       + (size_t)(i + POS) * (RES * RES)
                       + (size_t)(j + POS) * RES
                       + (size_t)(kk + POS);
#pragma unroll
        for (int b = 0; b < BATCH; ++b) {
            float2 v = make_float2(acc0[b] + m.x, acc1[b] + m.y);
            *(float2*)&out[(size_t)b * OUT_PER_B + o] = v;   // 8B-aligned
        }
    } else {
        // ---- periphery zeroing, F4PT float4s per thread at 256-thread stride
        // (coalesced 1 KB per store instr per wave); skip float4 groups fully
        // inside the core (exact partition: kk in [16,48) == groups [4,12)).
        const size_t base = (size_t)(bid - CORE_BLOCKS) * (256 * F4PT)
                          + threadIdx.x;
        vfloat4* o4 = (vfloat4*)out;
        const int g = (int)(base & 15);            // k-group: invariant over s
        const bool gc = (g >= 4) & (g < 12);
        const vfloat4 zz = (vfloat4){0.f, 0.f, 0.f, 0.f};
#pragma unroll
        for (int s = 0; s < F4PT; ++s) {
            const size_t p = base + (size_t)s * 256;
            const int rem = (int)(p & 65535);      // within one (b,c) 64^3/4 chunk
            const int i = rem >> 10;
            const int j = (rem >> 4) & 63;
            const bool in_core = gc & (i >= POS) & (i < POS + CORE) &
                                      (j >= POS) & (j < POS + CORE);
            // non-temporal: don't let the 235 MB zero stream thrash L2
            // against the 64 MB U read stream.
            if (!in_core) __builtin_nontemporal_store(zz, &o4[p]);
        }
    }
}

extern "C" void kernel_launch(void* const* d_in, const int* in_sizes, int n_in,
                              void* d_out, int out_size, void* d_ws, size_t ws_size,
                              hipStream_t stream) {
    const float* z  = (const float*)d_in[0];   // (32, 64)
    const float* U  = (const float*)d_in[1];   // (64, 262144)
    const float* L  = (const float*)d_in[2];   // (64,)
    const float* mu = (const float*)d_in[3];   // (262144,)
    float* out = (float*)d_out;                // (32, 8, 64, 64, 64)

    core_part_kernel<<<CORE_BLOCKS + ZERO_BLOCKS, 256, 0, stream>>>(U, mu, z, L, out);
}